// Round 8
// baseline (287.074 us; speedup 1.0000x reference)
//
#include <hip/hip_runtime.h>
#include <math.h>

#define NSITE 100
#define NOCC  50
#define DIM   128
#define KDET  4
#define NTAB  400                         // K*(N_UP+N_DOWN)
#define TP_FLOATS ((4 + 144) * NTAB)      // T then P' in ws

// ---------------------------------------------------------------------------
// R18: GEMM collapsed into T[4][400]/P'[144][400] table adds.
// R19-R22: register-resident LU variants: spill-or-barrier wall at 170-260us.
// R23: two-panel LU (25 live cols max): clean alloc, 181us @ VALUBusy 86%.
//      Diagnosis: ~2700 cross-lane ops/wave at ~7cyc each on the VALU pipe.
// R24/25: phase-2's 625 broadcasts readlane -> ds_bpermute (LDS pipe):
//      181 -> 141.7us (-22%), prediction confirmed. VALU still 87% busy;
//      remaining: 650 phase-1/3 update readlanes + DPP pivot chains.
// R26 (this round): convert phase-1/3 update broadcasts to ds_bpermute too
//      (pivot selection stays DPP/readlane -- serial, needs SGPRs).
//      LDS pipe ~1225 bpermute ~6-7K cyc/wave, still < VALU residue ~13K.
//      Bit-exact: same pre-update value, same fma, all lanes convergent.
// ---------------------------------------------------------------------------

// Wave64 max-reduction via DPP (VALU-only). Lane 63 ends with global max.
__device__ __forceinline__ unsigned dpp_max64_to_lane63(unsigned x) {
  unsigned t;
  t = (unsigned)__builtin_amdgcn_update_dpp((int)x, (int)x, 0x111, 0xf, 0xf, false);
  x = x > t ? x : t;
  t = (unsigned)__builtin_amdgcn_update_dpp((int)x, (int)x, 0x112, 0xf, 0xf, false);
  x = x > t ? x : t;
  t = (unsigned)__builtin_amdgcn_update_dpp((int)x, (int)x, 0x114, 0xf, 0xf, false);
  x = x > t ? x : t;
  t = (unsigned)__builtin_amdgcn_update_dpp((int)x, (int)x, 0x118, 0xf, 0xf, false);
  x = x > t ? x : t;
  t = (unsigned)__builtin_amdgcn_update_dpp((int)x, (int)x, 0x142, 0xa, 0xf, false);
  x = x > t ? x : t;
  t = (unsigned)__builtin_amdgcn_update_dpp((int)x, (int)x, 0x143, 0xc, 0xf, false);
  x = x > t ? x : t;
  return x;
}

// 25-wide repeat
#define REPC(X) X(0) X(1) X(2) X(3) X(4) X(5) X(6) X(7) X(8) X(9) \
  X(10) X(11) X(12) X(13) X(14) X(15) X(16) X(17) X(18) X(19) \
  X(20) X(21) X(22) X(23) X(24)

// ---- Precompute: T[c][j] = tok[c].W_j ; P'[s][j] = pos[s].W_j + b_j ------
__global__ __launch_bounds__(256) void tp_kernel(
    const float* __restrict__ tok, const float* __restrict__ pos,
    const float* __restrict__ W,   const float* __restrict__ bvec,
    float* __restrict__ T, float* __restrict__ P)
{
  const int gid = blockIdx.x * 256 + threadIdx.x;
  if (gid >= 148 * NTAB) return;
  const int row = gid / NTAB;
  const int col = gid - row * NTAB;
  const float4* h4 = (const float4*)((row < 4) ? (tok + (size_t)row * DIM)
                                               : (pos + (size_t)(row - 4) * DIM));
  const float4* w4 = (const float4*)(W + (size_t)col * DIM);
  float acc = 0.0f;
  #pragma unroll
  for (int i = 0; i < DIM / 4; ++i) {
    float4 a = h4[i], b = w4[i];
    acc = fmaf(a.x, b.x, acc);
    acc = fmaf(a.y, b.y, acc);
    acc = fmaf(a.z, b.z, acc);
    acc = fmaf(a.w, b.w, acc);
  }
  if (row < 4) T[(size_t)row * NTAB + col] = acc;
  else         P[(size_t)(row - 4) * NTAB + col] = acc + bvec[col];
}

// One block per (batch, spin). Wave w handles determinant k=w.
// Lane r owns row r of phi. Two-panel LU; see header comment.
__global__ __launch_bounds__(256)
__attribute__((amdgpu_waves_per_eu(6)))
void det_kernel(
    const int*   __restrict__ configs,   // (B,100) int32
    const float* __restrict__ T,         // (4,400)
    const float* __restrict__ P,         // (144,400)  includes bias
    double*      __restrict__ dets)      // (B,2,4,2)  {logdet, sign}
{
  const int b    = blockIdx.x;
  const int spin = blockIdx.y;

  __shared__ int cfg[NSITE];
  __shared__ int idx[NOCC];
  __shared__ unsigned long long omask[2];
  __shared__ float stash[4][25][64];     // per-wave multiplier stash

  const int tid = threadIdx.x;

  // ---- wave-parallel occupied-index build (ballot + prefix popcount) ----
  bool occv = false;
  if (tid < NSITE) {
    const int c = configs[(size_t)b * NSITE + tid];
    cfg[tid] = c;
    occv = (spin == 0) ? (c == 1 || c == 3) : (c == 2 || c == 3);
  }
  const unsigned long long bal = __ballot(occv);
  if ((tid & 63) == 0 && tid < 128) omask[tid >> 6] = bal;
  __syncthreads();
  if (tid < NSITE) {
    const unsigned long long m0 = omask[0], m1 = omask[1];
    const int mtot = __popcll(m0) + __popcll(m1);
    const int need = (mtot < NOCC) ? (NOCC - mtot) : 0;
    int pocc;
    if (tid >= 64) pocc = __popcll(m0) + __popcll(m1 & ((1ull << (tid - 64)) - 1ull));
    else           pocc = __popcll(m0 & ((1ull << tid) - 1ull));
    const int punocc = tid - pocc;
    const bool sel = occv ? (pocc < NOCC) : (punocc < need);
    const int  poscap = (pocc  < NOCC) ? pocc  : NOCC;
    const int  pfill  = (punocc < need) ? punocc : need;
    if (sel) idx[poscap + pfill] = tid;
  }
  __syncthreads();

  const int lane = tid & 63;
  const int wave = tid >> 6;
  const int wave_u  = __builtin_amdgcn_readfirstlane(wave);
  const int colbase = spin * 200 + wave_u * 50;          // uniform

  const bool act  = (lane < NOCC);
  const int  site = idx[act ? lane : 0];
  const int  cc0  = cfg[site];
  const float* Trow = T + (size_t)cc0  * NTAB + colbase;
  const float* Prow = P + (size_t)site * NTAB + colbase;
  // colbase multiple of 50 -> byte offset multiple of 200 -> 8-aligned
  const float2* T2 = (const float2*)Trow;
  const float2* P2 = (const float2*)Prow;

  // ================= phase 1: cols 0..24 in c0..c24 =================
  #define DECLC(i) float c##i;
  REPC(DECLC)
  #undef DECLC
  #define LQ(i0, i1) { float2 a = T2[(i0) / 2], d = P2[(i0) / 2]; \
      c##i0 = a.x + d.x; c##i1 = a.y + d.y; }
  LQ(0, 1)  LQ(2, 3)  LQ(4, 5)  LQ(6, 7)  LQ(8, 9)  LQ(10, 11)
  LQ(12, 13) LQ(14, 15) LQ(16, 17) LQ(18, 19) LQ(20, 21) LQ(22, 23)
  #undef LQ
  c24 = Trow[24] + Prow[24];
  #define ZC(i) c##i = act ? c##i : 0.0f;
  REPC(ZC)
  #undef ZC

  unsigned aliveq = act ? 0xFFFFFFFFu : 0u;   // per-lane alive mask
  float    mant_prod = 1.0f;                  // pivot mantissa product < 2^50
  int      esum = 0;
  unsigned sgnx = 0u;
  unsigned long long chosen = 0ull;
  int      invsum = 0;
  const unsigned lu = (unsigned)lane;
  unsigned long long pp[3] = {0ull, 0ull, 0ull};  // packed pivot lanes, 6b ea

  // update chains, c family (broadcast via LDS crossbar, not VALU):
  // UCF_N applies UC to regs N..24
  #define UC(L) { const float pc = __int_as_float( \
      __builtin_amdgcn_ds_bpermute(pa, __float_as_int(c##L))); \
      c##L = fmaf(-mult, pc, c##L); }
  #define UCF_25
  #define UCF_24 UC(24)
  #define UCF_23 UC(23) UCF_24
  #define UCF_22 UC(22) UCF_23
  #define UCF_21 UC(21) UCF_22
  #define UCF_20 UC(20) UCF_21
  #define UCF_19 UC(19) UCF_20
  #define UCF_18 UC(18) UCF_19
  #define UCF_17 UC(17) UCF_18
  #define UCF_16 UC(16) UCF_17
  #define UCF_15 UC(15) UCF_16
  #define UCF_14 UC(14) UCF_15
  #define UCF_13 UC(13) UCF_14
  #define UCF_12 UC(12) UCF_13
  #define UCF_11 UC(11) UCF_12
  #define UCF_10 UC(10) UCF_11
  #define UCF_9  UC(9)  UCF_10
  #define UCF_8  UC(8)  UCF_9
  #define UCF_7  UC(7)  UCF_8
  #define UCF_6  UC(6)  UCF_7
  #define UCF_5  UC(5)  UCF_6
  #define UCF_4  UC(4)  UCF_5
  #define UCF_3  UC(3)  UCF_4
  #define UCF_2  UC(2)  UCF_3
  #define UCF_1  UC(1)  UCF_2

  // Step J (global step J, 0..24): pivot, account, stash mult, update tail.
  #define P1STEP(J, N) { \
    unsigned key = ((__float_as_uint(c##J) & 0x7FFFFFC0u) | lu) & aliveq; \
    key = dpp_max64_to_lane63(key); \
    const int p = __builtin_amdgcn_readlane((int)key, 63) & 63; \
    const unsigned pb = (unsigned)__builtin_amdgcn_readlane( \
        __float_as_int(c##J), p); \
    esum += (int)((pb >> 23) & 0xFFu) - 127; \
    sgnx ^= (pb & 0x80000000u); \
    mant_prod *= __uint_as_float((pb & 0x007FFFFFu) | 0x3F800000u); \
    invsum += __popcll(chosen >> (p + 1)); \
    chosen |= 1ull << (unsigned)p; \
    aliveq = (lane == p) ? 0u : aliveq; \
    pp[(J) / 10] |= ((unsigned long long)(unsigned)p) << (6 * ((J) % 10)); \
    const float piv = __uint_as_float(pb); \
    float r0 = __builtin_amdgcn_rcpf(piv); \
    r0 = fmaf(fmaf(-piv, r0, 1.0f), r0, r0); \
    const float rp = ((pb & 0x7FFFFFFFu) != 0u) ? r0 : 0.0f; \
    const float mult = __uint_as_float(__float_as_uint(c##J * rp) & aliveq); \
    stash[wave_u][(J)][lane] = mult; \
    const int pa = p << 2; \
    UCF_##N \
  }

  P1STEP(0,1)   P1STEP(1,2)   P1STEP(2,3)   P1STEP(3,4)   P1STEP(4,5)
  P1STEP(5,6)   P1STEP(6,7)   P1STEP(7,8)   P1STEP(8,9)   P1STEP(9,10)
  P1STEP(10,11) P1STEP(11,12) P1STEP(12,13) P1STEP(13,14) P1STEP(14,15)
  P1STEP(15,16) P1STEP(16,17) P1STEP(17,18) P1STEP(18,19) P1STEP(19,20)
  P1STEP(20,21) P1STEP(21,22) P1STEP(22,23) P1STEP(23,24) P1STEP(24,25)
  #undef P1STEP

  // ================= phase 2: cols 25..49, replay steps 0..24 ============
  // Broadcasts ride the LDS pipe (ds_bpermute, no LDS storage) so the
  // saturated VALU pipe only executes the fmas. Bit-exact vs readlane.
  #define DECLT(i) float t##i;
  REPC(DECLT)
  #undef DECLT
  #define LT(i) t##i = Trow[25 + (i)] + Prow[25 + (i)];
  REPC(LT)
  #undef LT
  #define ZT(i) t##i = act ? t##i : 0.0f;
  REPC(ZT)
  #undef ZT

  // bpermute update: pc pulled from lane (pa>>2) through LDS crossbar
  #define BT(L) { const float pc = __int_as_float( \
      __builtin_amdgcn_ds_bpermute(pa, __float_as_int(t##L))); \
      t##L = fmaf(-mult, pc, t##L); }

  // replay step J on all 25 trailing cols (mult from stash, p from pack);
  // sched_barrier every 6 bounds in-flight bpermute results (reg pressure)
  #define P2J(J) { \
    const int pa = ((int)((pp[(J) / 10] >> (6 * ((J) % 10))) & 63ull)) << 2; \
    const float mult = stash[wave_u][(J)][lane]; \
    BT(0)  BT(1)  BT(2)  BT(3)  BT(4)  BT(5) \
    __builtin_amdgcn_sched_barrier(0); \
    BT(6)  BT(7)  BT(8)  BT(9)  BT(10) BT(11) \
    __builtin_amdgcn_sched_barrier(0); \
    BT(12) BT(13) BT(14) BT(15) BT(16) BT(17) \
    __builtin_amdgcn_sched_barrier(0); \
    BT(18) BT(19) BT(20) BT(21) BT(22) BT(23) BT(24) \
    __builtin_amdgcn_sched_barrier(0); \
  }
  P2J(0)  P2J(1)  P2J(2)  P2J(3)  P2J(4)  P2J(5)  P2J(6)  P2J(7)
  P2J(8)  P2J(9)  P2J(10) P2J(11) P2J(12) P2J(13) P2J(14) P2J(15)
  P2J(16) P2J(17) P2J(18) P2J(19) P2J(20) P2J(21) P2J(22) P2J(23)
  P2J(24)
  #undef P2J
  #undef BT

  // ================= phase 3: factor steps 25..49 on t0..t24 =============
  #define UT(L) { const float pc = __int_as_float( \
      __builtin_amdgcn_ds_bpermute(pa, __float_as_int(t##L))); \
      t##L = fmaf(-mult, pc, t##L); }
  #define UTF_25
  #define UTF_24 UT(24)
  #define UTF_23 UT(23) UTF_24
  #define UTF_22 UT(22) UTF_23
  #define UTF_21 UT(21) UTF_22
  #define UTF_20 UT(20) UTF_21
  #define UTF_19 UT(19) UTF_20
  #define UTF_18 UT(18) UTF_19
  #define UTF_17 UT(17) UTF_18
  #define UTF_16 UT(16) UTF_17
  #define UTF_15 UT(15) UTF_16
  #define UTF_14 UT(14) UTF_15
  #define UTF_13 UT(13) UTF_14
  #define UTF_12 UT(12) UTF_13
  #define UTF_11 UT(11) UTF_12
  #define UTF_10 UT(10) UTF_11
  #define UTF_9  UT(9)  UTF_10
  #define UTF_8  UT(8)  UTF_9
  #define UTF_7  UT(7)  UTF_8
  #define UTF_6  UT(6)  UTF_7
  #define UTF_5  UT(5)  UTF_6
  #define UTF_4  UT(4)  UTF_5
  #define UTF_3  UT(3)  UTF_4
  #define UTF_2  UT(2)  UTF_3
  #define UTF_1  UT(1)  UTF_2

  #define P3STEP(L, N) { \
    unsigned key = ((__float_as_uint(t##L) & 0x7FFFFFC0u) | lu) & aliveq; \
    key = dpp_max64_to_lane63(key); \
    const int p = __builtin_amdgcn_readlane((int)key, 63) & 63; \
    const unsigned pb = (unsigned)__builtin_amdgcn_readlane( \
        __float_as_int(t##L), p); \
    esum += (int)((pb >> 23) & 0xFFu) - 127; \
    sgnx ^= (pb & 0x80000000u); \
    mant_prod *= __uint_as_float((pb & 0x007FFFFFu) | 0x3F800000u); \
    invsum += __popcll(chosen >> (p + 1)); \
    chosen |= 1ull << (unsigned)p; \
    aliveq = (lane == p) ? 0u : aliveq; \
    const float piv = __uint_as_float(pb); \
    float r0 = __builtin_amdgcn_rcpf(piv); \
    r0 = fmaf(fmaf(-piv, r0, 1.0f), r0, r0); \
    const float rp = ((pb & 0x7FFFFFFFu) != 0u) ? r0 : 0.0f; \
    const float mult = __uint_as_float(__float_as_uint(t##L * rp) & aliveq); \
    const int pa = p << 2; \
    UTF_##N \
  }

  P3STEP(0,1)   P3STEP(1,2)   P3STEP(2,3)   P3STEP(3,4)   P3STEP(4,5)
  P3STEP(5,6)   P3STEP(6,7)   P3STEP(7,8)   P3STEP(8,9)   P3STEP(9,10)
  P3STEP(10,11) P3STEP(11,12) P3STEP(12,13) P3STEP(13,14) P3STEP(14,15)
  P3STEP(15,16) P3STEP(16,17) P3STEP(17,18) P3STEP(18,19) P3STEP(19,20)
  P3STEP(20,21) P3STEP(21,22) P3STEP(22,23) P3STEP(23,24) P3STEP(24,25)
  #undef P3STEP
  #undef UT
  #undef UC

  const double logdet =
      log((double)mant_prod) + (double)esum * 0.6931471805599453;
  const int sgn = (((sgnx >> 31) + (unsigned)invsum) & 1u) ? -1 : 1;

  if (lane == 0) {
    size_t o = (((size_t)b * 2 + spin) * KDET + wave) * 2;
    dets[o]     = logdet;
    dets[o + 1] = (double)sgn;
  }
}

// PLANAR complex64 output: out[0..B) = log_abs (real), out[B..2B) = phase (imag)
__global__ __launch_bounds__(256) void combine_kernel(
    const double* __restrict__ dets, float* __restrict__ out, int B)
{
  int b = blockIdx.x * blockDim.x + threadIdx.x;
  if (b >= B) return;
  const double* du = dets + ((size_t)b * 2 + 0) * KDET * 2;
  const double* dd = dets + ((size_t)b * 2 + 1) * KDET * 2;
  double t[KDET], s[KDET], m = -1e300;
  #pragma unroll
  for (int k = 0; k < KDET; ++k) {
    t[k] = du[2 * k] + dd[2 * k];
    s[k] = du[2 * k + 1] * dd[2 * k + 1];
    if (t[k] > m) m = t[k];
  }
  double sum = 0.0;
  #pragma unroll
  for (int k = 0; k < KDET; ++k) {
    if (t[k] > -1e290) sum += s[k] * exp(t[k] - m);
  }
  double p  = (m > -1e290) ? exp(m) * fabs(sum) : 0.0;
  double la = log(p + 1e-30);                    // reproduce ref clamp exactly
  float phase = (sum >= 0.0) ? 0.0f : 3.14159265358979f;
  out[b]     = (float)la;
  out[B + b] = phase;
}

extern "C" void kernel_launch(void* const* d_in, const int* in_sizes, int n_in,
                              void* d_out, int out_size, void* d_ws, size_t ws_size,
                              hipStream_t stream) {
  const int*   configs = (const int*)  d_in[0];
  const float* tok     = (const float*)d_in[1];
  const float* pos     = (const float*)d_in[2];
  const float* W       = (const float*)d_in[3];
  const float* bv      = (const float*)d_in[4];

  float*  wsf  = (float*)d_ws;
  float*  T    = wsf;                       // 4*400 floats
  float*  P    = wsf + 4 * NTAB;            // 144*400 floats
  double* dets = (double*)(wsf + TP_FLOATS);  // 236800B offset, 8-aligned
  const int B = in_sizes[0] / NSITE;        // total ws: ~499KB

  tp_kernel<<<(148 * NTAB + 255) / 256, 256, 0, stream>>>(tok, pos, W, bv, T, P);
  dim3 grid(B, 2);
  det_kernel<<<grid, 256, 0, stream>>>(configs, T, P, dets);
  combine_kernel<<<(B + 255) / 256, 256, 0, stream>>>(dets, (float*)d_out, B);
}

// Round 9
// 240.022 us; speedup vs baseline: 1.1960x; 1.1960x over previous
//
#include <hip/hip_runtime.h>
#include <math.h>

#define NSITE 100
#define NOCC  50
#define DIM   128
#define KDET  4
#define NTAB  400                         // K*(N_UP+N_DOWN)
#define TP_FLOATS ((4 + 144) * NTAB)      // T then P' in ws

// ---------------------------------------------------------------------------
// R18: GEMM collapsed into T[4][400]/P'[144][400] table adds.
// R19-R22: register-resident LU variants: spill-or-barrier wall 170-260us.
// R23: two-panel LU (25 live cols max): clean alloc, 181us @ VALUBusy 86%.
//      ~2700 cross-lane ops/wave at ~7cyc each on the VALU pipe.
// R24/25: phase-2 broadcasts readlane -> ds_bpermute: 181 -> 141.7us.
//      Works because phase 2 has 25 INDEPENDENT per-column chains (ILP
//      hides LDS crossbar latency).
// R26: converting ALL phase-1/3 updates to bpermute REGRESSED (237us,
//      VALUBusy 39%): the pivot-critical column update put a full LDS
//      round-trip on the loop-carried pivot chain, x100 steps.
// R27 (this round): revert phases 1/3 to readlane, then HYBRID phase 3:
//      next-pivot column via readlane (pivot chain stays pure VALU),
//      trailing 276 updates via bpermute (phase-2-style per-column ILP).
//      Phase 1 untouched (DS-throughput headroom uncertain; phase-3-only
//      is robust under both DS models).
// ---------------------------------------------------------------------------

// Wave64 max-reduction via DPP (VALU-only). Lane 63 ends with global max.
__device__ __forceinline__ unsigned dpp_max64_to_lane63(unsigned x) {
  unsigned t;
  t = (unsigned)__builtin_amdgcn_update_dpp((int)x, (int)x, 0x111, 0xf, 0xf, false);
  x = x > t ? x : t;
  t = (unsigned)__builtin_amdgcn_update_dpp((int)x, (int)x, 0x112, 0xf, 0xf, false);
  x = x > t ? x : t;
  t = (unsigned)__builtin_amdgcn_update_dpp((int)x, (int)x, 0x114, 0xf, 0xf, false);
  x = x > t ? x : t;
  t = (unsigned)__builtin_amdgcn_update_dpp((int)x, (int)x, 0x118, 0xf, 0xf, false);
  x = x > t ? x : t;
  t = (unsigned)__builtin_amdgcn_update_dpp((int)x, (int)x, 0x142, 0xa, 0xf, false);
  x = x > t ? x : t;
  t = (unsigned)__builtin_amdgcn_update_dpp((int)x, (int)x, 0x143, 0xc, 0xf, false);
  x = x > t ? x : t;
  return x;
}

// 25-wide repeat
#define REPC(X) X(0) X(1) X(2) X(3) X(4) X(5) X(6) X(7) X(8) X(9) \
  X(10) X(11) X(12) X(13) X(14) X(15) X(16) X(17) X(18) X(19) \
  X(20) X(21) X(22) X(23) X(24)

// ---- Precompute: T[c][j] = tok[c].W_j ; P'[s][j] = pos[s].W_j + b_j ------
__global__ __launch_bounds__(256) void tp_kernel(
    const float* __restrict__ tok, const float* __restrict__ pos,
    const float* __restrict__ W,   const float* __restrict__ bvec,
    float* __restrict__ T, float* __restrict__ P)
{
  const int gid = blockIdx.x * 256 + threadIdx.x;
  if (gid >= 148 * NTAB) return;
  const int row = gid / NTAB;
  const int col = gid - row * NTAB;
  const float4* h4 = (const float4*)((row < 4) ? (tok + (size_t)row * DIM)
                                               : (pos + (size_t)(row - 4) * DIM));
  const float4* w4 = (const float4*)(W + (size_t)col * DIM);
  float acc = 0.0f;
  #pragma unroll
  for (int i = 0; i < DIM / 4; ++i) {
    float4 a = h4[i], b = w4[i];
    acc = fmaf(a.x, b.x, acc);
    acc = fmaf(a.y, b.y, acc);
    acc = fmaf(a.z, b.z, acc);
    acc = fmaf(a.w, b.w, acc);
  }
  if (row < 4) T[(size_t)row * NTAB + col] = acc;
  else         P[(size_t)(row - 4) * NTAB + col] = acc + bvec[col];
}

// One block per (batch, spin). Wave w handles determinant k=w.
// Lane r owns row r of phi. Two-panel LU; see header comment.
__global__ __launch_bounds__(256)
__attribute__((amdgpu_waves_per_eu(6)))
void det_kernel(
    const int*   __restrict__ configs,   // (B,100) int32
    const float* __restrict__ T,         // (4,400)
    const float* __restrict__ P,         // (144,400)  includes bias
    double*      __restrict__ dets)      // (B,2,4,2)  {logdet, sign}
{
  const int b    = blockIdx.x;
  const int spin = blockIdx.y;

  __shared__ int cfg[NSITE];
  __shared__ int idx[NOCC];
  __shared__ unsigned long long omask[2];
  __shared__ float stash[4][25][64];     // per-wave multiplier stash

  const int tid = threadIdx.x;

  // ---- wave-parallel occupied-index build (ballot + prefix popcount) ----
  bool occv = false;
  if (tid < NSITE) {
    const int c = configs[(size_t)b * NSITE + tid];
    cfg[tid] = c;
    occv = (spin == 0) ? (c == 1 || c == 3) : (c == 2 || c == 3);
  }
  const unsigned long long bal = __ballot(occv);
  if ((tid & 63) == 0 && tid < 128) omask[tid >> 6] = bal;
  __syncthreads();
  if (tid < NSITE) {
    const unsigned long long m0 = omask[0], m1 = omask[1];
    const int mtot = __popcll(m0) + __popcll(m1);
    const int need = (mtot < NOCC) ? (NOCC - mtot) : 0;
    int pocc;
    if (tid >= 64) pocc = __popcll(m0) + __popcll(m1 & ((1ull << (tid - 64)) - 1ull));
    else           pocc = __popcll(m0 & ((1ull << tid) - 1ull));
    const int punocc = tid - pocc;
    const bool sel = occv ? (pocc < NOCC) : (punocc < need);
    const int  poscap = (pocc  < NOCC) ? pocc  : NOCC;
    const int  pfill  = (punocc < need) ? punocc : need;
    if (sel) idx[poscap + pfill] = tid;
  }
  __syncthreads();

  const int lane = tid & 63;
  const int wave = tid >> 6;
  const int wave_u  = __builtin_amdgcn_readfirstlane(wave);
  const int colbase = spin * 200 + wave_u * 50;          // uniform

  const bool act  = (lane < NOCC);
  const int  site = idx[act ? lane : 0];
  const int  cc0  = cfg[site];
  const float* Trow = T + (size_t)cc0  * NTAB + colbase;
  const float* Prow = P + (size_t)site * NTAB + colbase;
  // colbase multiple of 50 -> byte offset multiple of 200 -> 8-aligned
  const float2* T2 = (const float2*)Trow;
  const float2* P2 = (const float2*)Prow;

  // ================= phase 1: cols 0..24 in c0..c24 =================
  #define DECLC(i) float c##i;
  REPC(DECLC)
  #undef DECLC
  #define LQ(i0, i1) { float2 a = T2[(i0) / 2], d = P2[(i0) / 2]; \
      c##i0 = a.x + d.x; c##i1 = a.y + d.y; }
  LQ(0, 1)  LQ(2, 3)  LQ(4, 5)  LQ(6, 7)  LQ(8, 9)  LQ(10, 11)
  LQ(12, 13) LQ(14, 15) LQ(16, 17) LQ(18, 19) LQ(20, 21) LQ(22, 23)
  #undef LQ
  c24 = Trow[24] + Prow[24];
  #define ZC(i) c##i = act ? c##i : 0.0f;
  REPC(ZC)
  #undef ZC

  unsigned aliveq = act ? 0xFFFFFFFFu : 0u;   // per-lane alive mask
  float    mant_prod = 1.0f;                  // pivot mantissa product < 2^50
  int      esum = 0;
  unsigned sgnx = 0u;
  unsigned long long chosen = 0ull;
  int      invsum = 0;
  const unsigned lu = (unsigned)lane;
  unsigned long long pp[3] = {0ull, 0ull, 0ull};  // packed pivot lanes, 6b ea

  // update chains, c family (readlane broadcast -- VALU):
  // UCF_N applies UC to regs N..24
  #define UC(L) { const float pc = __int_as_float( \
      __builtin_amdgcn_readlane(__float_as_int(c##L), p)); \
      c##L = fmaf(-mult, pc, c##L); }
  #define UCF_25
  #define UCF_24 UC(24)
  #define UCF_23 UC(23) UCF_24
  #define UCF_22 UC(22) UCF_23
  #define UCF_21 UC(21) UCF_22
  #define UCF_20 UC(20) UCF_21
  #define UCF_19 UC(19) UCF_20
  #define UCF_18 UC(18) UCF_19
  #define UCF_17 UC(17) UCF_18
  #define UCF_16 UC(16) UCF_17
  #define UCF_15 UC(15) UCF_16
  #define UCF_14 UC(14) UCF_15
  #define UCF_13 UC(13) UCF_14
  #define UCF_12 UC(12) UCF_13
  #define UCF_11 UC(11) UCF_12
  #define UCF_10 UC(10) UCF_11
  #define UCF_9  UC(9)  UCF_10
  #define UCF_8  UC(8)  UCF_9
  #define UCF_7  UC(7)  UCF_8
  #define UCF_6  UC(6)  UCF_7
  #define UCF_5  UC(5)  UCF_6
  #define UCF_4  UC(4)  UCF_5
  #define UCF_3  UC(3)  UCF_4
  #define UCF_2  UC(2)  UCF_3
  #define UCF_1  UC(1)  UCF_2

  // Step J (global step J, 0..24): pivot, account, stash mult, update tail.
  #define P1STEP(J, N) { \
    unsigned key = ((__float_as_uint(c##J) & 0x7FFFFFC0u) | lu) & aliveq; \
    key = dpp_max64_to_lane63(key); \
    const int p = __builtin_amdgcn_readlane((int)key, 63) & 63; \
    const unsigned pb = (unsigned)__builtin_amdgcn_readlane( \
        __float_as_int(c##J), p); \
    esum += (int)((pb >> 23) & 0xFFu) - 127; \
    sgnx ^= (pb & 0x80000000u); \
    mant_prod *= __uint_as_float((pb & 0x007FFFFFu) | 0x3F800000u); \
    invsum += __popcll(chosen >> (p + 1)); \
    chosen |= 1ull << (unsigned)p; \
    aliveq = (lane == p) ? 0u : aliveq; \
    pp[(J) / 10] |= ((unsigned long long)(unsigned)p) << (6 * ((J) % 10)); \
    const float piv = __uint_as_float(pb); \
    float r0 = __builtin_amdgcn_rcpf(piv); \
    r0 = fmaf(fmaf(-piv, r0, 1.0f), r0, r0); \
    const float rp = ((pb & 0x7FFFFFFFu) != 0u) ? r0 : 0.0f; \
    const float mult = __uint_as_float(__float_as_uint(c##J * rp) & aliveq); \
    stash[wave_u][(J)][lane] = mult; \
    UCF_##N \
  }

  P1STEP(0,1)   P1STEP(1,2)   P1STEP(2,3)   P1STEP(3,4)   P1STEP(4,5)
  P1STEP(5,6)   P1STEP(6,7)   P1STEP(7,8)   P1STEP(8,9)   P1STEP(9,10)
  P1STEP(10,11) P1STEP(11,12) P1STEP(12,13) P1STEP(13,14) P1STEP(14,15)
  P1STEP(15,16) P1STEP(16,17) P1STEP(17,18) P1STEP(18,19) P1STEP(19,20)
  P1STEP(20,21) P1STEP(21,22) P1STEP(22,23) P1STEP(23,24) P1STEP(24,25)
  #undef P1STEP

  // ================= phase 2: cols 25..49, replay steps 0..24 ============
  // Broadcasts ride the LDS pipe (ds_bpermute, no LDS storage) so the
  // saturated VALU pipe only executes the fmas. Bit-exact vs readlane.
  #define DECLT(i) float t##i;
  REPC(DECLT)
  #undef DECLT
  #define LT(i) t##i = Trow[25 + (i)] + Prow[25 + (i)];
  REPC(LT)
  #undef LT
  #define ZT(i) t##i = act ? t##i : 0.0f;
  REPC(ZT)
  #undef ZT

  // bpermute update: pc pulled from lane (pa>>2) through LDS crossbar
  #define BT(L) { const float pc = __int_as_float( \
      __builtin_amdgcn_ds_bpermute(pa, __float_as_int(t##L))); \
      t##L = fmaf(-mult, pc, t##L); }

  // replay step J on all 25 trailing cols (mult from stash, p from pack);
  // sched_barrier every 6 bounds in-flight bpermute results (reg pressure)
  #define P2J(J) { \
    const int pa = ((int)((pp[(J) / 10] >> (6 * ((J) % 10))) & 63ull)) << 2; \
    const float mult = stash[wave_u][(J)][lane]; \
    BT(0)  BT(1)  BT(2)  BT(3)  BT(4)  BT(5) \
    __builtin_amdgcn_sched_barrier(0); \
    BT(6)  BT(7)  BT(8)  BT(9)  BT(10) BT(11) \
    __builtin_amdgcn_sched_barrier(0); \
    BT(12) BT(13) BT(14) BT(15) BT(16) BT(17) \
    __builtin_amdgcn_sched_barrier(0); \
    BT(18) BT(19) BT(20) BT(21) BT(22) BT(23) BT(24) \
    __builtin_amdgcn_sched_barrier(0); \
  }
  P2J(0)  P2J(1)  P2J(2)  P2J(3)  P2J(4)  P2J(5)  P2J(6)  P2J(7)
  P2J(8)  P2J(9)  P2J(10) P2J(11) P2J(12) P2J(13) P2J(14) P2J(15)
  P2J(16) P2J(17) P2J(18) P2J(19) P2J(20) P2J(21) P2J(22) P2J(23)
  P2J(24)
  #undef P2J
  #undef BT

  // ================= phase 3: factor steps 25..49 on t0..t24 =============
  // Hybrid pipelined: critical (next-pivot) column via readlane keeps the
  // loop-carried pivot chain pure-VALU; trailing columns via bpermute get
  // phase-2-style per-column ILP. Bit-identical op sequence vs R23.
  int   p3;
  float rp3;
  { // prologue: pivot of t0 (global step 25)
    unsigned key = ((__float_as_uint(t0) & 0x7FFFFFC0u) | lu) & aliveq;
    key = dpp_max64_to_lane63(key);
    p3 = __builtin_amdgcn_readlane((int)key, 63) & 63;
    const unsigned pb = (unsigned)__builtin_amdgcn_readlane(
        __float_as_int(t0), p3);
    esum += (int)((pb >> 23) & 0xFFu) - 127;
    sgnx ^= (pb & 0x80000000u);
    mant_prod *= __uint_as_float((pb & 0x007FFFFFu) | 0x3F800000u);
    invsum += __popcll(chosen >> (p3 + 1));
    chosen |= 1ull << (unsigned)p3;
    aliveq = (lane == p3) ? 0u : aliveq;
    const float piv = __uint_as_float(pb);
    float r0 = __builtin_amdgcn_rcpf(piv);
    r0 = fmaf(fmaf(-piv, r0, 1.0f), r0, r0);
    rp3 = ((pb & 0x7FFFFFFFu) != 0u) ? r0 : 0.0f;
  }

  // trailing bpermute update (pa3 = old pivot lane byte addr)
  #define BU(C) { const float pc = __int_as_float( \
      __builtin_amdgcn_ds_bpermute(pa3, __float_as_int(t##C))); \
      t##C = fmaf(-mult, pc, t##C); }
  #define BTRAIL_24
  #define BTRAIL_23 BU(24)
  #define BTRAIL_22 BU(23) BTRAIL_23
  #define BTRAIL_21 BU(22) BTRAIL_22
  #define BTRAIL_20 BU(21) BTRAIL_21
  #define BTRAIL_19 BU(20) BTRAIL_20
  #define BTRAIL_18 BU(19) BTRAIL_19
  #define BTRAIL_17 BU(18) BTRAIL_18
  #define BTRAIL_16 BU(17) BTRAIL_17
  #define BTRAIL_15 BU(16) BTRAIL_16
  #define BTRAIL_14 BU(15) BTRAIL_15
  #define BTRAIL_13 BU(14) BTRAIL_14
  #define BTRAIL_12 BU(13) BTRAIL_13
  #define BTRAIL_11 BU(12) BTRAIL_12
  #define BTRAIL_10 BU(11) BTRAIL_11
  #define BTRAIL_9  BU(10) BTRAIL_10
  #define BTRAIL_8  BU(9)  BTRAIL_9
  #define BTRAIL_7  BU(8)  BTRAIL_8
  #define BTRAIL_6  BU(7)  BTRAIL_7
  #define BTRAIL_5  BU(6)  BTRAIL_6
  #define BTRAIL_4  BU(5)  BTRAIL_5
  #define BTRAIL_3  BU(4)  BTRAIL_4
  #define BTRAIL_2  BU(3)  BTRAIL_3
  #define BTRAIL_1  BU(2)  BTRAIL_2

  // Step: eliminate with pivot (p3, rp3) of column L; critical update of
  // t_{L1} via readlane; launch next key chain; trailing via bpermute;
  // then select+account pivot of t_{L1}.
  #define P3S(L, L1) { \
    const float mult = __uint_as_float(__float_as_uint(t##L * rp3) & aliveq); \
    { const float pc0 = __int_as_float( \
          __builtin_amdgcn_readlane(__float_as_int(t##L1), p3)); \
      t##L1 = fmaf(-mult, pc0, t##L1); } \
    unsigned key = ((__float_as_uint(t##L1) & 0x7FFFFFC0u) | lu) & aliveq; \
    key = dpp_max64_to_lane63(key); \
    const int pa3 = p3 << 2; \
    BTRAIL_##L1 \
    p3 = __builtin_amdgcn_readlane((int)key, 63) & 63; \
    const unsigned pb = (unsigned)__builtin_amdgcn_readlane( \
        __float_as_int(t##L1), p3); \
    esum += (int)((pb >> 23) & 0xFFu) - 127; \
    sgnx ^= (pb & 0x80000000u); \
    mant_prod *= __uint_as_float((pb & 0x007FFFFFu) | 0x3F800000u); \
    invsum += __popcll(chosen >> (p3 + 1)); \
    chosen |= 1ull << (unsigned)p3; \
    aliveq = (lane == p3) ? 0u : aliveq; \
    const float piv = __uint_as_float(pb); \
    float r0 = __builtin_amdgcn_rcpf(piv); \
    r0 = fmaf(fmaf(-piv, r0, 1.0f), r0, r0); \
    rp3 = ((pb & 0x7FFFFFFFu) != 0u) ? r0 : 0.0f; \
  }

  P3S(0,1)   P3S(1,2)   P3S(2,3)   P3S(3,4)   P3S(4,5)   P3S(5,6)
  P3S(6,7)   P3S(7,8)   P3S(8,9)   P3S(9,10)  P3S(10,11) P3S(11,12)
  P3S(12,13) P3S(13,14) P3S(14,15) P3S(15,16) P3S(16,17) P3S(17,18)
  P3S(18,19) P3S(19,20) P3S(20,21) P3S(21,22) P3S(22,23) P3S(23,24)
  #undef P3S
  #undef BU
  #undef UC

  const double logdet =
      log((double)mant_prod) + (double)esum * 0.6931471805599453;
  const int sgn = (((sgnx >> 31) + (unsigned)invsum) & 1u) ? -1 : 1;

  if (lane == 0) {
    size_t o = (((size_t)b * 2 + spin) * KDET + wave) * 2;
    dets[o]     = logdet;
    dets[o + 1] = (double)sgn;
  }
}

// PLANAR complex64 output: out[0..B) = log_abs (real), out[B..2B) = phase (imag)
__global__ __launch_bounds__(256) void combine_kernel(
    const double* __restrict__ dets, float* __restrict__ out, int B)
{
  int b = blockIdx.x * blockDim.x + threadIdx.x;
  if (b >= B) return;
  const double* du = dets + ((size_t)b * 2 + 0) * KDET * 2;
  const double* dd = dets + ((size_t)b * 2 + 1) * KDET * 2;
  double t[KDET], s[KDET], m = -1e300;
  #pragma unroll
  for (int k = 0; k < KDET; ++k) {
    t[k] = du[2 * k] + dd[2 * k];
    s[k] = du[2 * k + 1] * dd[2 * k + 1];
    if (t[k] > m) m = t[k];
  }
  double sum = 0.0;
  #pragma unroll
  for (int k = 0; k < KDET; ++k) {
    if (t[k] > -1e290) sum += s[k] * exp(t[k] - m);
  }
  double p  = (m > -1e290) ? exp(m) * fabs(sum) : 0.0;
  double la = log(p + 1e-30);                    // reproduce ref clamp exactly
  float phase = (sum >= 0.0) ? 0.0f : 3.14159265358979f;
  out[b]     = (float)la;
  out[B + b] = phase;
}

extern "C" void kernel_launch(void* const* d_in, const int* in_sizes, int n_in,
                              void* d_out, int out_size, void* d_ws, size_t ws_size,
                              hipStream_t stream) {
  const int*   configs = (const int*)  d_in[0];
  const float* tok     = (const float*)d_in[1];
  const float* pos     = (const float*)d_in[2];
  const float* W       = (const float*)d_in[3];
  const float* bv      = (const float*)d_in[4];

  float*  wsf  = (float*)d_ws;
  float*  T    = wsf;                       // 4*400 floats
  float*  P    = wsf + 4 * NTAB;            // 144*400 floats
  double* dets = (double*)(wsf + TP_FLOATS);  // 236800B offset, 8-aligned
  const int B = in_sizes[0] / NSITE;        // total ws: ~499KB

  tp_kernel<<<(148 * NTAB + 255) / 256, 256, 0, stream>>>(tok, pos, W, bv, T, P);
  dim3 grid(B, 2);
  det_kernel<<<grid, 256, 0, stream>>>(configs, T, P, dets);
  combine_kernel<<<(B + 255) / 256, 256, 0, stream>>>(dets, (float*)d_out, B);
}

// Round 10
// 195.687 us; speedup vs baseline: 1.4670x; 1.2266x over previous
//
#include <hip/hip_runtime.h>
#include <math.h>

#define NSITE 100
#define NOCC  50
#define DIM   128
#define KDET  4
#define NTAB  400                         // K*(N_UP+N_DOWN)
#define TP_FLOATS ((4 + 144) * NTAB)      // T then P' in ws

// ---------------------------------------------------------------------------
// R18: GEMM collapsed into T[4][400]/P'[144][400] table adds.
// R19-R22: register-resident LU variants: spill-or-barrier wall 170-260us.
// R23: two-panel LU (25 live cols max): clean alloc, 181us @ VALUBusy 86%.
//      ~2700 cross-lane ops/wave at ~7cyc each on the VALU pipe.
// R24/25: phase-2 broadcasts readlane -> ds_bpermute: 181 -> 141.7us.
//      Works: phase 2 = 25 INDEPENDENT per-column chains (ILP hides LDS
//      crossbar latency).
// R26: ALL updates via bpermute: 237us (VALUBusy 39%) -- LDS round-trip on
//      the loop-carried pivot chain.
// R27: hybrid phase 3 (readlane next-pivot col, bpermute trailing): 185us,
//      VALUBusy 59%. The bpermute'd column becomes critical ONE step later;
//      ~40cyc slack < LDS latency. LESSON: serial phases tolerate NO LDS
//      dependency within ~1 step of the pivot chain. Phases 1/3 stay
//      readlane permanently.
// R28 (this round): revert to R25 (best, 141.7us) + occupancy lever:
//      stash [4][25][64]->[4][25][50] (25.6->20KB), cfg/idx -> bytes.
//      Block LDS 26.6KB -> 20.2KB -> EXACTLY 8 blocks/CU (32 waves, was
//      24) + waves_per_eu(8). Phase-2 garbage reads by lanes>=50 are
//      harmless (dead-lane values never consumed); stash writes predicated.
// ---------------------------------------------------------------------------

// Wave64 max-reduction via DPP (VALU-only). Lane 63 ends with global max.
__device__ __forceinline__ unsigned dpp_max64_to_lane63(unsigned x) {
  unsigned t;
  t = (unsigned)__builtin_amdgcn_update_dpp((int)x, (int)x, 0x111, 0xf, 0xf, false);
  x = x > t ? x : t;
  t = (unsigned)__builtin_amdgcn_update_dpp((int)x, (int)x, 0x112, 0xf, 0xf, false);
  x = x > t ? x : t;
  t = (unsigned)__builtin_amdgcn_update_dpp((int)x, (int)x, 0x114, 0xf, 0xf, false);
  x = x > t ? x : t;
  t = (unsigned)__builtin_amdgcn_update_dpp((int)x, (int)x, 0x118, 0xf, 0xf, false);
  x = x > t ? x : t;
  t = (unsigned)__builtin_amdgcn_update_dpp((int)x, (int)x, 0x142, 0xa, 0xf, false);
  x = x > t ? x : t;
  t = (unsigned)__builtin_amdgcn_update_dpp((int)x, (int)x, 0x143, 0xc, 0xf, false);
  x = x > t ? x : t;
  return x;
}

// 25-wide repeat
#define REPC(X) X(0) X(1) X(2) X(3) X(4) X(5) X(6) X(7) X(8) X(9) \
  X(10) X(11) X(12) X(13) X(14) X(15) X(16) X(17) X(18) X(19) \
  X(20) X(21) X(22) X(23) X(24)

// ---- Precompute: T[c][j] = tok[c].W_j ; P'[s][j] = pos[s].W_j + b_j ------
__global__ __launch_bounds__(256) void tp_kernel(
    const float* __restrict__ tok, const float* __restrict__ pos,
    const float* __restrict__ W,   const float* __restrict__ bvec,
    float* __restrict__ T, float* __restrict__ P)
{
  const int gid = blockIdx.x * 256 + threadIdx.x;
  if (gid >= 148 * NTAB) return;
  const int row = gid / NTAB;
  const int col = gid - row * NTAB;
  const float4* h4 = (const float4*)((row < 4) ? (tok + (size_t)row * DIM)
                                               : (pos + (size_t)(row - 4) * DIM));
  const float4* w4 = (const float4*)(W + (size_t)col * DIM);
  float acc = 0.0f;
  #pragma unroll
  for (int i = 0; i < DIM / 4; ++i) {
    float4 a = h4[i], b = w4[i];
    acc = fmaf(a.x, b.x, acc);
    acc = fmaf(a.y, b.y, acc);
    acc = fmaf(a.z, b.z, acc);
    acc = fmaf(a.w, b.w, acc);
  }
  if (row < 4) T[(size_t)row * NTAB + col] = acc;
  else         P[(size_t)(row - 4) * NTAB + col] = acc + bvec[col];
}

// One block per (batch, spin). Wave w handles determinant k=w.
// Lane r owns row r of phi. Two-panel LU; see header comment.
__global__ __launch_bounds__(256)
__attribute__((amdgpu_waves_per_eu(8)))
void det_kernel(
    const int*   __restrict__ configs,   // (B,100) int32
    const float* __restrict__ T,         // (4,400)
    const float* __restrict__ P,         // (144,400)  includes bias
    double*      __restrict__ dets)      // (B,2,4,2)  {logdet, sign}
{
  const int b    = blockIdx.x;
  const int spin = blockIdx.y;

  __shared__ unsigned long long omask[2];
  __shared__ float stash[4][25][50];       // per-wave multiplier stash (20KB)
  __shared__ unsigned char cfg8[NSITE];
  __shared__ unsigned char idx8[NOCC];

  const int tid = threadIdx.x;

  // ---- wave-parallel occupied-index build (ballot + prefix popcount) ----
  bool occv = false;
  if (tid < NSITE) {
    const int c = configs[(size_t)b * NSITE + tid];
    cfg8[tid] = (unsigned char)c;
    occv = (spin == 0) ? (c == 1 || c == 3) : (c == 2 || c == 3);
  }
  const unsigned long long bal = __ballot(occv);
  if ((tid & 63) == 0 && tid < 128) omask[tid >> 6] = bal;
  __syncthreads();
  if (tid < NSITE) {
    const unsigned long long m0 = omask[0], m1 = omask[1];
    const int mtot = __popcll(m0) + __popcll(m1);
    const int need = (mtot < NOCC) ? (NOCC - mtot) : 0;
    int pocc;
    if (tid >= 64) pocc = __popcll(m0) + __popcll(m1 & ((1ull << (tid - 64)) - 1ull));
    else           pocc = __popcll(m0 & ((1ull << tid) - 1ull));
    const int punocc = tid - pocc;
    const bool sel = occv ? (pocc < NOCC) : (punocc < need);
    const int  poscap = (pocc  < NOCC) ? pocc  : NOCC;
    const int  pfill  = (punocc < need) ? punocc : need;
    if (sel) idx8[poscap + pfill] = (unsigned char)tid;
  }
  __syncthreads();

  const int lane = tid & 63;
  const int wave = tid >> 6;
  const int wave_u  = __builtin_amdgcn_readfirstlane(wave);
  const int colbase = spin * 200 + wave_u * 50;          // uniform

  const bool act  = (lane < NOCC);
  const int  site = idx8[act ? lane : 0];
  const int  cc0  = cfg8[site];
  const float* Trow = T + (size_t)cc0  * NTAB + colbase;
  const float* Prow = P + (size_t)site * NTAB + colbase;
  // colbase multiple of 50 -> byte offset multiple of 200 -> 8-aligned
  const float2* T2 = (const float2*)Trow;
  const float2* P2 = (const float2*)Prow;

  // ================= phase 1: cols 0..24 in c0..c24 =================
  #define DECLC(i) float c##i;
  REPC(DECLC)
  #undef DECLC
  #define LQ(i0, i1) { float2 a = T2[(i0) / 2], d = P2[(i0) / 2]; \
      c##i0 = a.x + d.x; c##i1 = a.y + d.y; }
  LQ(0, 1)  LQ(2, 3)  LQ(4, 5)  LQ(6, 7)  LQ(8, 9)  LQ(10, 11)
  LQ(12, 13) LQ(14, 15) LQ(16, 17) LQ(18, 19) LQ(20, 21) LQ(22, 23)
  #undef LQ
  c24 = Trow[24] + Prow[24];
  #define ZC(i) c##i = act ? c##i : 0.0f;
  REPC(ZC)
  #undef ZC

  unsigned aliveq = act ? 0xFFFFFFFFu : 0u;   // per-lane alive mask
  float    mant_prod = 1.0f;                  // pivot mantissa product < 2^50
  int      esum = 0;
  unsigned sgnx = 0u;
  unsigned long long chosen = 0ull;
  int      invsum = 0;
  const unsigned lu = (unsigned)lane;
  unsigned long long pp[3] = {0ull, 0ull, 0ull};  // packed pivot lanes, 6b ea

  // update chains, c family (readlane broadcast -- VALU):
  // UCF_N applies UC to regs N..24
  #define UC(L) { const float pc = __int_as_float( \
      __builtin_amdgcn_readlane(__float_as_int(c##L), p)); \
      c##L = fmaf(-mult, pc, c##L); }
  #define UCF_25
  #define UCF_24 UC(24)
  #define UCF_23 UC(23) UCF_24
  #define UCF_22 UC(22) UCF_23
  #define UCF_21 UC(21) UCF_22
  #define UCF_20 UC(20) UCF_21
  #define UCF_19 UC(19) UCF_20
  #define UCF_18 UC(18) UCF_19
  #define UCF_17 UC(17) UCF_18
  #define UCF_16 UC(16) UCF_17
  #define UCF_15 UC(15) UCF_16
  #define UCF_14 UC(14) UCF_15
  #define UCF_13 UC(13) UCF_14
  #define UCF_12 UC(12) UCF_13
  #define UCF_11 UC(11) UCF_12
  #define UCF_10 UC(10) UCF_11
  #define UCF_9  UC(9)  UCF_10
  #define UCF_8  UC(8)  UCF_9
  #define UCF_7  UC(7)  UCF_8
  #define UCF_6  UC(6)  UCF_7
  #define UCF_5  UC(5)  UCF_6
  #define UCF_4  UC(4)  UCF_5
  #define UCF_3  UC(3)  UCF_4
  #define UCF_2  UC(2)  UCF_3
  #define UCF_1  UC(1)  UCF_2

  // Step J (global step J, 0..24): pivot, account, stash mult, update tail.
  #define P1STEP(J, N) { \
    unsigned key = ((__float_as_uint(c##J) & 0x7FFFFFC0u) | lu) & aliveq; \
    key = dpp_max64_to_lane63(key); \
    const int p = __builtin_amdgcn_readlane((int)key, 63) & 63; \
    const unsigned pb = (unsigned)__builtin_amdgcn_readlane( \
        __float_as_int(c##J), p); \
    esum += (int)((pb >> 23) & 0xFFu) - 127; \
    sgnx ^= (pb & 0x80000000u); \
    mant_prod *= __uint_as_float((pb & 0x007FFFFFu) | 0x3F800000u); \
    invsum += __popcll(chosen >> (p + 1)); \
    chosen |= 1ull << (unsigned)p; \
    aliveq = (lane == p) ? 0u : aliveq; \
    pp[(J) / 10] |= ((unsigned long long)(unsigned)p) << (6 * ((J) % 10)); \
    const float piv = __uint_as_float(pb); \
    float r0 = __builtin_amdgcn_rcpf(piv); \
    r0 = fmaf(fmaf(-piv, r0, 1.0f), r0, r0); \
    const float rp = ((pb & 0x7FFFFFFFu) != 0u) ? r0 : 0.0f; \
    const float mult = __uint_as_float(__float_as_uint(c##J * rp) & aliveq); \
    if (act) stash[wave_u][(J)][lane] = mult; \
    UCF_##N \
  }

  P1STEP(0,1)   P1STEP(1,2)   P1STEP(2,3)   P1STEP(3,4)   P1STEP(4,5)
  P1STEP(5,6)   P1STEP(6,7)   P1STEP(7,8)   P1STEP(8,9)   P1STEP(9,10)
  P1STEP(10,11) P1STEP(11,12) P1STEP(12,13) P1STEP(13,14) P1STEP(14,15)
  P1STEP(15,16) P1STEP(16,17) P1STEP(17,18) P1STEP(18,19) P1STEP(19,20)
  P1STEP(20,21) P1STEP(21,22) P1STEP(22,23) P1STEP(23,24) P1STEP(24,25)
  #undef P1STEP

  // ================= phase 2: cols 25..49, replay steps 0..24 ============
  // Broadcasts ride the LDS pipe (ds_bpermute, no LDS storage) so the
  // saturated VALU pipe only executes the fmas. Bit-exact vs readlane.
  // Lanes >=50 read garbage mult (next stash row) -- harmless: dead-lane
  // values are never consumed (bpermute pulls only pivot lanes <50, keys
  // aliveq-masked, accounting broadcast-redundant, output from lane 0).
  #define DECLT(i) float t##i;
  REPC(DECLT)
  #undef DECLT
  #define LT(i) t##i = Trow[25 + (i)] + Prow[25 + (i)];
  REPC(LT)
  #undef LT
  #define ZT(i) t##i = act ? t##i : 0.0f;
  REPC(ZT)
  #undef ZT

  // bpermute update: pc pulled from lane (pa>>2) through LDS crossbar
  #define BT(L) { const float pc = __int_as_float( \
      __builtin_amdgcn_ds_bpermute(pa, __float_as_int(t##L))); \
      t##L = fmaf(-mult, pc, t##L); }

  // replay step J on all 25 trailing cols (mult from stash, p from pack);
  // sched_barrier every 6 bounds in-flight bpermute results (reg pressure)
  #define P2J(J) { \
    const int pa = ((int)((pp[(J) / 10] >> (6 * ((J) % 10))) & 63ull)) << 2; \
    const float mult = stash[wave_u][(J)][lane < NOCC ? lane : 0]; \
    BT(0)  BT(1)  BT(2)  BT(3)  BT(4)  BT(5) \
    __builtin_amdgcn_sched_barrier(0); \
    BT(6)  BT(7)  BT(8)  BT(9)  BT(10) BT(11) \
    __builtin_amdgcn_sched_barrier(0); \
    BT(12) BT(13) BT(14) BT(15) BT(16) BT(17) \
    __builtin_amdgcn_sched_barrier(0); \
    BT(18) BT(19) BT(20) BT(21) BT(22) BT(23) BT(24) \
    __builtin_amdgcn_sched_barrier(0); \
  }
  P2J(0)  P2J(1)  P2J(2)  P2J(3)  P2J(4)  P2J(5)  P2J(6)  P2J(7)
  P2J(8)  P2J(9)  P2J(10) P2J(11) P2J(12) P2J(13) P2J(14) P2J(15)
  P2J(16) P2J(17) P2J(18) P2J(19) P2J(20) P2J(21) P2J(22) P2J(23)
  P2J(24)
  #undef P2J
  #undef BT

  // ================= phase 3: factor steps 25..49 on t0..t24 =============
  #define UT(L) { const float pc = __int_as_float( \
      __builtin_amdgcn_readlane(__float_as_int(t##L), p)); \
      t##L = fmaf(-mult, pc, t##L); }
  #define UTF_25
  #define UTF_24 UT(24)
  #define UTF_23 UT(23) UTF_24
  #define UTF_22 UT(22) UTF_23
  #define UTF_21 UT(21) UTF_22
  #define UTF_20 UT(20) UTF_21
  #define UTF_19 UT(19) UTF_20
  #define UTF_18 UT(18) UTF_19
  #define UTF_17 UT(17) UTF_18
  #define UTF_16 UT(16) UTF_17
  #define UTF_15 UT(15) UTF_16
  #define UTF_14 UT(14) UTF_15
  #define UTF_13 UT(13) UTF_14
  #define UTF_12 UT(12) UTF_13
  #define UTF_11 UT(11) UTF_12
  #define UTF_10 UT(10) UTF_11
  #define UTF_9  UT(9)  UTF_10
  #define UTF_8  UT(8)  UTF_9
  #define UTF_7  UT(7)  UTF_8
  #define UTF_6  UT(6)  UTF_7
  #define UTF_5  UT(5)  UTF_6
  #define UTF_4  UT(4)  UTF_5
  #define UTF_3  UT(3)  UTF_4
  #define UTF_2  UT(2)  UTF_3
  #define UTF_1  UT(1)  UTF_2

  #define P3STEP(L, N) { \
    unsigned key = ((__float_as_uint(t##L) & 0x7FFFFFC0u) | lu) & aliveq; \
    key = dpp_max64_to_lane63(key); \
    const int p = __builtin_amdgcn_readlane((int)key, 63) & 63; \
    const unsigned pb = (unsigned)__builtin_amdgcn_readlane( \
        __float_as_int(t##L), p); \
    esum += (int)((pb >> 23) & 0xFFu) - 127; \
    sgnx ^= (pb & 0x80000000u); \
    mant_prod *= __uint_as_float((pb & 0x007FFFFFu) | 0x3F800000u); \
    invsum += __popcll(chosen >> (p + 1)); \
    chosen |= 1ull << (unsigned)p; \
    aliveq = (lane == p) ? 0u : aliveq; \
    const float piv = __uint_as_float(pb); \
    float r0 = __builtin_amdgcn_rcpf(piv); \
    r0 = fmaf(fmaf(-piv, r0, 1.0f), r0, r0); \
    const float rp = ((pb & 0x7FFFFFFFu) != 0u) ? r0 : 0.0f; \
    const float mult = __uint_as_float(__float_as_uint(t##L * rp) & aliveq); \
    UTF_##N \
  }

  P3STEP(0,1)   P3STEP(1,2)   P3STEP(2,3)   P3STEP(3,4)   P3STEP(4,5)
  P3STEP(5,6)   P3STEP(6,7)   P3STEP(7,8)   P3STEP(8,9)   P3STEP(9,10)
  P3STEP(10,11) P3STEP(11,12) P3STEP(12,13) P3STEP(13,14) P3STEP(14,15)
  P3STEP(15,16) P3STEP(16,17) P3STEP(17,18) P3STEP(18,19) P3STEP(19,20)
  P3STEP(20,21) P3STEP(21,22) P3STEP(22,23) P3STEP(23,24) P3STEP(24,25)
  #undef P3STEP
  #undef UT
  #undef UC

  const double logdet =
      log((double)mant_prod) + (double)esum * 0.6931471805599453;
  const int sgn = (((sgnx >> 31) + (unsigned)invsum) & 1u) ? -1 : 1;

  if (lane == 0) {
    size_t o = (((size_t)b * 2 + spin) * KDET + wave) * 2;
    dets[o]     = logdet;
    dets[o + 1] = (double)sgn;
  }
}

// PLANAR complex64 output: out[0..B) = log_abs (real), out[B..2B) = phase (imag)
__global__ __launch_bounds__(256) void combine_kernel(
    const double* __restrict__ dets, float* __restrict__ out, int B)
{
  int b = blockIdx.x * blockDim.x + threadIdx.x;
  if (b >= B) return;
  const double* du = dets + ((size_t)b * 2 + 0) * KDET * 2;
  const double* dd = dets + ((size_t)b * 2 + 1) * KDET * 2;
  double t[KDET], s[KDET], m = -1e300;
  #pragma unroll
  for (int k = 0; k < KDET; ++k) {
    t[k] = du[2 * k] + dd[2 * k];
    s[k] = du[2 * k + 1] * dd[2 * k + 1];
    if (t[k] > m) m = t[k];
  }
  double sum = 0.0;
  #pragma unroll
  for (int k = 0; k < KDET; ++k) {
    if (t[k] > -1e290) sum += s[k] * exp(t[k] - m);
  }
  double p  = (m > -1e290) ? exp(m) * fabs(sum) : 0.0;
  double la = log(p + 1e-30);                    // reproduce ref clamp exactly
  float phase = (sum >= 0.0) ? 0.0f : 3.14159265358979f;
  out[b]     = (float)la;
  out[B + b] = phase;
}

extern "C" void kernel_launch(void* const* d_in, const int* in_sizes, int n_in,
                              void* d_out, int out_size, void* d_ws, size_t ws_size,
                              hipStream_t stream) {
  const int*   configs = (const int*)  d_in[0];
  const float* tok     = (const float*)d_in[1];
  const float* pos     = (const float*)d_in[2];
  const float* W       = (const float*)d_in[3];
  const float* bv      = (const float*)d_in[4];

  float*  wsf  = (float*)d_ws;
  float*  T    = wsf;                       // 4*400 floats
  float*  P    = wsf + 4 * NTAB;            // 144*400 floats
  double* dets = (double*)(wsf + TP_FLOATS);  // 236800B offset, 8-aligned
  const int B = in_sizes[0] / NSITE;        // total ws: ~499KB

  tp_kernel<<<(148 * NTAB + 255) / 256, 256, 0, stream>>>(tok, pos, W, bv, T, P);
  dim3 grid(B, 2);
  det_kernel<<<grid, 256, 0, stream>>>(configs, T, P, dets);
  combine_kernel<<<(B + 255) / 256, 256, 0, stream>>>(dets, (float*)d_out, B);
}

// Round 11
// 195.178 us; speedup vs baseline: 1.4708x; 1.0026x over previous
//
#include <hip/hip_runtime.h>
#include <math.h>

#define NSITE 100
#define NOCC  50
#define DIM   128
#define KDET  4
#define NTAB  400                         // K*(N_UP+N_DOWN)
#define TP_FLOATS ((4 + 144) * NTAB)      // T then P' in ws

// ---------------------------------------------------------------------------
// R18: GEMM collapsed into T[4][400]/P'[144][400] table adds.
// R23: two-panel LU (25 live cols max): clean alloc, 181us @ VALUBusy 86%.
// R24/25: phase-2 broadcasts -> ds_bpermute (LDS pipe): 141.7us. Phase 2's
//      25 independent per-column chains hide crossbar latency.
// R26/R27: bpermute anywhere near the serial pivot chain regresses hard
//      (237/185us). Phases 1/3 stay readlane PERMANENTLY.
// R28: LDS diet -> 8 blocks/CU (occupancy 60->72%): det 140us, flat.
//      Falsifier fired: latency already hidden; det is cross-lane-ISSUE
//      bound (~18.5K cyc/wave). Intra-det rebalancing exhausted.
// R29 (this round): attack the ~56us OUTSIDE det:
//   (a) fuse combine into det: block = 1 batch, 512thr = 8 waves =
//       2 spins x 4 dets; LU unchanged (bit-identical); results via LDS;
//       thread 0 runs the identical double-precision combine. Kills one
//       kernel launch + dets HBM round-trip. LDS exactly 40960B ->
//       4 blocks/CU -> full 32 waves/CU.
//   (b) tp split-K x4: 4 lanes/output, shfl_xor tree combine -> 14.5
//       waves/CU (was 3.6, latency-starved). ~1ulp T/P change (same
//       scale as R19's rcp change which passed).
// ---------------------------------------------------------------------------

// Wave64 max-reduction via DPP (VALU-only). Lane 63 ends with global max.
__device__ __forceinline__ unsigned dpp_max64_to_lane63(unsigned x) {
  unsigned t;
  t = (unsigned)__builtin_amdgcn_update_dpp((int)x, (int)x, 0x111, 0xf, 0xf, false);
  x = x > t ? x : t;
  t = (unsigned)__builtin_amdgcn_update_dpp((int)x, (int)x, 0x112, 0xf, 0xf, false);
  x = x > t ? x : t;
  t = (unsigned)__builtin_amdgcn_update_dpp((int)x, (int)x, 0x114, 0xf, 0xf, false);
  x = x > t ? x : t;
  t = (unsigned)__builtin_amdgcn_update_dpp((int)x, (int)x, 0x118, 0xf, 0xf, false);
  x = x > t ? x : t;
  t = (unsigned)__builtin_amdgcn_update_dpp((int)x, (int)x, 0x142, 0xa, 0xf, false);
  x = x > t ? x : t;
  t = (unsigned)__builtin_amdgcn_update_dpp((int)x, (int)x, 0x143, 0xc, 0xf, false);
  x = x > t ? x : t;
  return x;
}

// 25-wide repeat
#define REPC(X) X(0) X(1) X(2) X(3) X(4) X(5) X(6) X(7) X(8) X(9) \
  X(10) X(11) X(12) X(13) X(14) X(15) X(16) X(17) X(18) X(19) \
  X(20) X(21) X(22) X(23) X(24)

// ---- Precompute: T[c][j] = tok[c].W_j ; P'[s][j] = pos[s].W_j + b_j ------
// Split-K x4: lanes (4q+h) handle quarter h of output q; tree-combine via
// shfl_xor(1),(2); lane h==0 writes. 925 blocks -> ~14.5 waves/CU.
__global__ __launch_bounds__(256) void tp_kernel(
    const float* __restrict__ tok, const float* __restrict__ pos,
    const float* __restrict__ W,   const float* __restrict__ bvec,
    float* __restrict__ T, float* __restrict__ P)
{
  const int gid = blockIdx.x * 256 + threadIdx.x;
  if (gid >= 148 * NTAB * 4) return;
  const int q   = gid >> 2;
  const int h   = gid & 3;
  const int row = q / NTAB;
  const int col = q - row * NTAB;
  const float4* h4 = (const float4*)((row < 4) ? (tok + (size_t)row * DIM)
                                               : (pos + (size_t)(row - 4) * DIM));
  const float4* w4 = (const float4*)(W + (size_t)col * DIM);
  float acc = 0.0f;
  #pragma unroll
  for (int i = 0; i < 8; ++i) {
    float4 a = h4[h * 8 + i], b = w4[h * 8 + i];
    acc = fmaf(a.x, b.x, acc);
    acc = fmaf(a.y, b.y, acc);
    acc = fmaf(a.z, b.z, acc);
    acc = fmaf(a.w, b.w, acc);
  }
  acc += __shfl_xor(acc, 1);
  acc += __shfl_xor(acc, 2);
  if (h == 0) {
    if (row < 4) T[(size_t)row * NTAB + col] = acc;
    else         P[(size_t)(row - 4) * NTAB + col] = acc + bvec[col];
  }
}

// One block per batch. 8 waves: wave w -> spin = w>>2, det k = w&3.
// Lane r owns row r of phi. Two-panel LU per wave; combine fused at end.
__global__ __launch_bounds__(512)
__attribute__((amdgpu_waves_per_eu(8)))
void det_kernel(
    const int*   __restrict__ configs,   // (B,100) int32
    const float* __restrict__ T,         // (4,400)
    const float* __restrict__ P,         // (144,400)  includes bias
    float*       __restrict__ out,       // planar complex64
    int B)
{
  const int b = blockIdx.x;

  __shared__ float stash[8][25][50];       // 40000B multiplier stash
  __shared__ int cfg[NSITE];               // 400B
  __shared__ int idxs[2][NOCC];            // 400B
  __shared__ unsigned long long omask[2][2];  // 32B
  __shared__ double detl[2][KDET][2];      // 128B  -> total 40960B exactly

  const int tid = threadIdx.x;

  // ---- wave-parallel occupied-index build for BOTH spins ----
  int  cval = 0;
  bool ou = false, od = false;
  if (tid < NSITE) {
    cval = configs[(size_t)b * NSITE + tid];
    cfg[tid] = cval;
    ou = (cval == 1) || (cval == 3);
    od = (cval == 2) || (cval == 3);
  }
  const unsigned long long balu = __ballot(ou);
  const unsigned long long bald = __ballot(od);
  if ((tid & 63) == 0 && tid < 128) {
    omask[0][tid >> 6] = balu;
    omask[1][tid >> 6] = bald;
  }
  __syncthreads();
  if (tid < NSITE) {
    #pragma unroll
    for (int s = 0; s < 2; ++s) {
      const unsigned long long m0 = omask[s][0], m1 = omask[s][1];
      const bool occv = (s == 0) ? ou : od;
      const int mtot = __popcll(m0) + __popcll(m1);
      const int need = (mtot < NOCC) ? (NOCC - mtot) : 0;
      int pocc;
      if (tid >= 64) pocc = __popcll(m0) + __popcll(m1 & ((1ull << (tid - 64)) - 1ull));
      else           pocc = __popcll(m0 & ((1ull << tid) - 1ull));
      const int punocc = tid - pocc;
      const bool sel = occv ? (pocc < NOCC) : (punocc < need);
      const int  poscap = (pocc  < NOCC) ? pocc  : NOCC;
      const int  pfill  = (punocc < need) ? punocc : need;
      if (sel) idxs[s][poscap + pfill] = tid;
    }
  }
  __syncthreads();

  const int lane   = tid & 63;
  const int wave   = tid >> 6;
  const int wave_u = __builtin_amdgcn_readfirstlane(wave);
  const int spin   = wave_u >> 2;
  const int kd     = wave_u & 3;
  const int colbase = spin * 200 + kd * 50;              // uniform

  const bool act  = (lane < NOCC);
  const int  site = idxs[spin][act ? lane : 0];
  const int  cc0  = cfg[site];
  const float* Trow = T + (size_t)cc0  * NTAB + colbase;
  const float* Prow = P + (size_t)site * NTAB + colbase;
  // colbase multiple of 50 -> byte offset multiple of 200 -> 8-aligned
  const float2* T2 = (const float2*)Trow;
  const float2* P2 = (const float2*)Prow;

  // ================= phase 1: cols 0..24 in c0..c24 =================
  #define DECLC(i) float c##i;
  REPC(DECLC)
  #undef DECLC
  #define LQ(i0, i1) { float2 a = T2[(i0) / 2], d = P2[(i0) / 2]; \
      c##i0 = a.x + d.x; c##i1 = a.y + d.y; }
  LQ(0, 1)  LQ(2, 3)  LQ(4, 5)  LQ(6, 7)  LQ(8, 9)  LQ(10, 11)
  LQ(12, 13) LQ(14, 15) LQ(16, 17) LQ(18, 19) LQ(20, 21) LQ(22, 23)
  #undef LQ
  c24 = Trow[24] + Prow[24];
  #define ZC(i) c##i = act ? c##i : 0.0f;
  REPC(ZC)
  #undef ZC

  unsigned aliveq = act ? 0xFFFFFFFFu : 0u;   // per-lane alive mask
  float    mant_prod = 1.0f;                  // pivot mantissa product < 2^50
  int      esum = 0;
  unsigned sgnx = 0u;
  unsigned long long chosen = 0ull;
  int      invsum = 0;
  const unsigned lu = (unsigned)lane;
  unsigned long long pp[3] = {0ull, 0ull, 0ull};  // packed pivot lanes, 6b ea

  // update chains, c family (readlane broadcast -- VALU):
  #define UC(L) { const float pc = __int_as_float( \
      __builtin_amdgcn_readlane(__float_as_int(c##L), p)); \
      c##L = fmaf(-mult, pc, c##L); }
  #define UCF_25
  #define UCF_24 UC(24)
  #define UCF_23 UC(23) UCF_24
  #define UCF_22 UC(22) UCF_23
  #define UCF_21 UC(21) UCF_22
  #define UCF_20 UC(20) UCF_21
  #define UCF_19 UC(19) UCF_20
  #define UCF_18 UC(18) UCF_19
  #define UCF_17 UC(17) UCF_18
  #define UCF_16 UC(16) UCF_17
  #define UCF_15 UC(15) UCF_16
  #define UCF_14 UC(14) UCF_15
  #define UCF_13 UC(13) UCF_14
  #define UCF_12 UC(12) UCF_13
  #define UCF_11 UC(11) UCF_12
  #define UCF_10 UC(10) UCF_11
  #define UCF_9  UC(9)  UCF_10
  #define UCF_8  UC(8)  UCF_9
  #define UCF_7  UC(7)  UCF_8
  #define UCF_6  UC(6)  UCF_7
  #define UCF_5  UC(5)  UCF_6
  #define UCF_4  UC(4)  UCF_5
  #define UCF_3  UC(3)  UCF_4
  #define UCF_2  UC(2)  UCF_3
  #define UCF_1  UC(1)  UCF_2

  // Step J (global step J, 0..24): pivot, account, stash mult, update tail.
  #define P1STEP(J, N) { \
    unsigned key = ((__float_as_uint(c##J) & 0x7FFFFFC0u) | lu) & aliveq; \
    key = dpp_max64_to_lane63(key); \
    const int p = __builtin_amdgcn_readlane((int)key, 63) & 63; \
    const unsigned pb = (unsigned)__builtin_amdgcn_readlane( \
        __float_as_int(c##J), p); \
    esum += (int)((pb >> 23) & 0xFFu) - 127; \
    sgnx ^= (pb & 0x80000000u); \
    mant_prod *= __uint_as_float((pb & 0x007FFFFFu) | 0x3F800000u); \
    invsum += __popcll(chosen >> (p + 1)); \
    chosen |= 1ull << (unsigned)p; \
    aliveq = (lane == p) ? 0u : aliveq; \
    pp[(J) / 10] |= ((unsigned long long)(unsigned)p) << (6 * ((J) % 10)); \
    const float piv = __uint_as_float(pb); \
    float r0 = __builtin_amdgcn_rcpf(piv); \
    r0 = fmaf(fmaf(-piv, r0, 1.0f), r0, r0); \
    const float rp = ((pb & 0x7FFFFFFFu) != 0u) ? r0 : 0.0f; \
    const float mult = __uint_as_float(__float_as_uint(c##J * rp) & aliveq); \
    if (act) stash[wave_u][(J)][lane] = mult; \
    UCF_##N \
  }

  P1STEP(0,1)   P1STEP(1,2)   P1STEP(2,3)   P1STEP(3,4)   P1STEP(4,5)
  P1STEP(5,6)   P1STEP(6,7)   P1STEP(7,8)   P1STEP(8,9)   P1STEP(9,10)
  P1STEP(10,11) P1STEP(11,12) P1STEP(12,13) P1STEP(13,14) P1STEP(14,15)
  P1STEP(15,16) P1STEP(16,17) P1STEP(17,18) P1STEP(18,19) P1STEP(19,20)
  P1STEP(20,21) P1STEP(21,22) P1STEP(22,23) P1STEP(23,24) P1STEP(24,25)
  #undef P1STEP

  // ================= phase 2: cols 25..49, replay steps 0..24 ============
  // Broadcasts ride the LDS pipe (ds_bpermute). Bit-exact vs readlane.
  #define DECLT(i) float t##i;
  REPC(DECLT)
  #undef DECLT
  #define LT(i) t##i = Trow[25 + (i)] + Prow[25 + (i)];
  REPC(LT)
  #undef LT
  #define ZT(i) t##i = act ? t##i : 0.0f;
  REPC(ZT)
  #undef ZT

  // bpermute update: pc pulled from lane (pa>>2) through LDS crossbar
  #define BT(L) { const float pc = __int_as_float( \
      __builtin_amdgcn_ds_bpermute(pa, __float_as_int(t##L))); \
      t##L = fmaf(-mult, pc, t##L); }

  #define P2J(J) { \
    const int pa = ((int)((pp[(J) / 10] >> (6 * ((J) % 10))) & 63ull)) << 2; \
    const float mult = stash[wave_u][(J)][lane < NOCC ? lane : 0]; \
    BT(0)  BT(1)  BT(2)  BT(3)  BT(4)  BT(5) \
    __builtin_amdgcn_sched_barrier(0); \
    BT(6)  BT(7)  BT(8)  BT(9)  BT(10) BT(11) \
    __builtin_amdgcn_sched_barrier(0); \
    BT(12) BT(13) BT(14) BT(15) BT(16) BT(17) \
    __builtin_amdgcn_sched_barrier(0); \
    BT(18) BT(19) BT(20) BT(21) BT(22) BT(23) BT(24) \
    __builtin_amdgcn_sched_barrier(0); \
  }
  P2J(0)  P2J(1)  P2J(2)  P2J(3)  P2J(4)  P2J(5)  P2J(6)  P2J(7)
  P2J(8)  P2J(9)  P2J(10) P2J(11) P2J(12) P2J(13) P2J(14) P2J(15)
  P2J(16) P2J(17) P2J(18) P2J(19) P2J(20) P2J(21) P2J(22) P2J(23)
  P2J(24)
  #undef P2J
  #undef BT

  // ================= phase 3: factor steps 25..49 on t0..t24 =============
  #define UT(L) { const float pc = __int_as_float( \
      __builtin_amdgcn_readlane(__float_as_int(t##L), p)); \
      t##L = fmaf(-mult, pc, t##L); }
  #define UTF_25
  #define UTF_24 UT(24)
  #define UTF_23 UT(23) UTF_24
  #define UTF_22 UT(22) UTF_23
  #define UTF_21 UT(21) UTF_22
  #define UTF_20 UT(20) UTF_21
  #define UTF_19 UT(19) UTF_20
  #define UTF_18 UT(18) UTF_19
  #define UTF_17 UT(17) UTF_18
  #define UTF_16 UT(16) UTF_17
  #define UTF_15 UT(15) UTF_16
  #define UTF_14 UT(14) UTF_15
  #define UTF_13 UT(13) UTF_14
  #define UTF_12 UT(12) UTF_13
  #define UTF_11 UT(11) UTF_12
  #define UTF_10 UT(10) UTF_11
  #define UTF_9  UT(9)  UTF_10
  #define UTF_8  UT(8)  UTF_9
  #define UTF_7  UT(7)  UTF_8
  #define UTF_6  UT(6)  UTF_7
  #define UTF_5  UT(5)  UTF_6
  #define UTF_4  UT(4)  UTF_5
  #define UTF_3  UT(3)  UTF_4
  #define UTF_2  UT(2)  UTF_3
  #define UTF_1  UT(1)  UTF_2

  #define P3STEP(L, N) { \
    unsigned key = ((__float_as_uint(t##L) & 0x7FFFFFC0u) | lu) & aliveq; \
    key = dpp_max64_to_lane63(key); \
    const int p = __builtin_amdgcn_readlane((int)key, 63) & 63; \
    const unsigned pb = (unsigned)__builtin_amdgcn_readlane( \
        __float_as_int(t##L), p); \
    esum += (int)((pb >> 23) & 0xFFu) - 127; \
    sgnx ^= (pb & 0x80000000u); \
    mant_prod *= __uint_as_float((pb & 0x007FFFFFu) | 0x3F800000u); \
    invsum += __popcll(chosen >> (p + 1)); \
    chosen |= 1ull << (unsigned)p; \
    aliveq = (lane == p) ? 0u : aliveq; \
    const float piv = __uint_as_float(pb); \
    float r0 = __builtin_amdgcn_rcpf(piv); \
    r0 = fmaf(fmaf(-piv, r0, 1.0f), r0, r0); \
    const float rp = ((pb & 0x7FFFFFFFu) != 0u) ? r0 : 0.0f; \
    const float mult = __uint_as_float(__float_as_uint(t##L * rp) & aliveq); \
    UTF_##N \
  }

  P3STEP(0,1)   P3STEP(1,2)   P3STEP(2,3)   P3STEP(3,4)   P3STEP(4,5)
  P3STEP(5,6)   P3STEP(6,7)   P3STEP(7,8)   P3STEP(8,9)   P3STEP(9,10)
  P3STEP(10,11) P3STEP(11,12) P3STEP(12,13) P3STEP(13,14) P3STEP(14,15)
  P3STEP(15,16) P3STEP(16,17) P3STEP(17,18) P3STEP(18,19) P3STEP(19,20)
  P3STEP(20,21) P3STEP(21,22) P3STEP(22,23) P3STEP(23,24) P3STEP(24,25)
  #undef P3STEP
  #undef UT
  #undef UC

  const double logdet =
      log((double)mant_prod) + (double)esum * 0.6931471805599453;
  const int sgn = (((sgnx >> 31) + (unsigned)invsum) & 1u) ? -1 : 1;

  if (lane == 0) {
    detl[spin][kd][0] = logdet;
    detl[spin][kd][1] = (double)sgn;
  }
  __syncthreads();

  // ---- fused combine (identical op order to the old combine_kernel) ----
  if (tid == 0) {
    double t[KDET], s[KDET], m = -1e300;
    #pragma unroll
    for (int k2 = 0; k2 < KDET; ++k2) {
      t[k2] = detl[0][k2][0] + detl[1][k2][0];
      s[k2] = detl[0][k2][1] * detl[1][k2][1];
      if (t[k2] > m) m = t[k2];
    }
    double sum = 0.0;
    #pragma unroll
    for (int k2 = 0; k2 < KDET; ++k2) {
      if (t[k2] > -1e290) sum += s[k2] * exp(t[k2] - m);
    }
    double pw = (m > -1e290) ? exp(m) * fabs(sum) : 0.0;
    double la = log(pw + 1e-30);                 // reproduce ref clamp exactly
    out[b]     = (float)la;
    out[B + b] = (sum >= 0.0) ? 0.0f : 3.14159265358979f;
  }
}

extern "C" void kernel_launch(void* const* d_in, const int* in_sizes, int n_in,
                              void* d_out, int out_size, void* d_ws, size_t ws_size,
                              hipStream_t stream) {
  const int*   configs = (const int*)  d_in[0];
  const float* tok     = (const float*)d_in[1];
  const float* pos     = (const float*)d_in[2];
  const float* W       = (const float*)d_in[3];
  const float* bv      = (const float*)d_in[4];

  float*  wsf  = (float*)d_ws;
  float*  T    = wsf;                       // 4*400 floats
  float*  P    = wsf + 4 * NTAB;            // 144*400 floats
  const int B = in_sizes[0] / NSITE;

  tp_kernel<<<(148 * NTAB * 4 + 255) / 256, 256, 0, stream>>>(tok, pos, W, bv, T, P);
  det_kernel<<<B, 512, 0, stream>>>(configs, T, P, (float*)d_out, B);
}